// Round 5
// baseline (722.261 us; speedup 1.0000x reference)
//
#include <hip/hip_runtime.h>
#include <stdint.h>

#define BATCH 32
#define SEQ   2048
#define HDIM  1024

typedef short short8 __attribute__((ext_vector_type(8)));
typedef float f32x4 __attribute__((ext_vector_type(4)));

__device__ __forceinline__ unsigned short f2b(float f) {
    unsigned u = __float_as_uint(f);
    u += 0x7FFFu + ((u >> 16) & 1u);   // round-to-nearest-even
    return (unsigned short)(u >> 16);
}
// pack hi16(a) | hi16(b)<<16 in one v_perm_b32 (bf16 truncation)
__device__ __forceinline__ unsigned pk_bf16(float a, float b) {
    return __builtin_amdgcn_perm(__float_as_uint(b), __float_as_uint(a), 0x07060302u);
}
__device__ __forceinline__ float fast_tanh(float x) {
    float ex = __expf(2.0f * x);
    return 1.0f - 2.0f / (ex + 1.0f);
}
__device__ __forceinline__ void gl2lds16(const unsigned short* g, unsigned short* l) {
    __builtin_amdgcn_global_load_lds(
        (const __attribute__((address_space(1))) unsigned int*)g,
        (__attribute__((address_space(3))) unsigned int*)l, 16, 0, 0);
}

// ---------------------------------------------------------------------------
// Kernel 1: per k-row (grid=1024): We row -> bf16 (RNE); qb = hidden.Wh^T + b;
// zero scores.
// ---------------------------------------------------------------------------
__global__ __launch_bounds__(256) void prep_kernel(
    const float* __restrict__ hidden, const float* __restrict__ attn_w,
    const float* __restrict__ attn_b, unsigned short* __restrict__ we_bf,
    float* __restrict__ qb, float* __restrict__ scores) {
    int k = blockIdx.x;
    int tid = threadIdx.x;

    if (tid < 64) scores[(size_t)k * 64 + tid] = 0.0f;

    {
        const float4* src = (const float4*)(attn_w + (size_t)k * 2048 + 1024);
        float4 v = src[tid];
        ushort4 o;
        o.x = f2b(v.x); o.y = f2b(v.y); o.z = f2b(v.z); o.w = f2b(v.w);
        ((ushort4*)(we_bf + (size_t)k * HDIM))[tid] = o;
    }

    float part[BATCH];
#pragma unroll
    for (int b = 0; b < BATCH; ++b) part[b] = 0.0f;
    const float* wrow = attn_w + (size_t)k * 2048;
    for (int h = tid; h < HDIM; h += 256) {
        float w = wrow[h];
#pragma unroll
        for (int b = 0; b < BATCH; ++b) part[b] += w * hidden[b * HDIM + h];
    }
    __shared__ float red[4][BATCH];
    int lane = tid & 63, wv = tid >> 6;
#pragma unroll
    for (int b = 0; b < BATCH; ++b) {
        float v = part[b];
        v += __shfl_xor(v, 1);  v += __shfl_xor(v, 2);  v += __shfl_xor(v, 4);
        v += __shfl_xor(v, 8);  v += __shfl_xor(v, 16); v += __shfl_xor(v, 32);
        if (lane == 0) red[wv][b] = v;
    }
    __syncthreads();
    if (tid < BATCH) {
        float v = red[0][tid] + red[1][tid] + red[2][tid] + red[3][tid] + attn_b[k];
        qb[(size_t)tid * HDIM + k] = v;
    }
}

// ---------------------------------------------------------------------------
// Kernel 2: score GEMM, 128x128 tile, BK=64, 256 threads (4 waves, 2Mx2N),
// per-wave output 64x64 (4x4 16x16 frags). Double-buffered 64KB static LDS
// -> 2 independent blocks/CU (the round-4 profile showed 1 block/CU: barrier
// drains had nothing to overlap with -> MfmaUtil 19%). Same single-barrier
// issue-early pipeline as round-4 (HW-verified correct, 0 bank conflicts):
// STAGE(t+1) issued at top of compute(t); DSW + one barrier at iter end.
// Swizzle (8 chunks/row @ BK=64): phys_chunk = chunk ^ (row&7). Bank audit:
// A ds_write_b128, A/B frag ds_read_b128 all land 32B/bank/instr (floor).
// XCD decode: 8 ntile-blocks of an mtile adjacent on one XCD -> A row-tile
// HBM-fetched ~once, L2-served 8x. Grid 4096 (16 blocks/CU -> 8 rounds).
// ---------------------------------------------------------------------------
__global__ __launch_bounds__(256, 2) void score_gemm_kernel(
    const float* __restrict__ enc, const unsigned short* __restrict__ we_bf,
    const float* __restrict__ qb, const float* __restrict__ v_w,
    float* __restrict__ scores) {
    __shared__ __align__(16) unsigned short As[2 * 8192];  // 2 x 128x64 bf16 = 32 KB
    __shared__ __align__(16) unsigned short Bs[2 * 8192];  // 32 KB

    int tid  = threadIdx.x;
    int lane = tid & 63, w = tid >> 6;     // 4 waves
    int wm = w & 1, wn = w >> 1;           // 2 x 2
    int i15 = lane & 15, q = lane >> 4;

    // XCD-aware decode: blockIdx%8 = XCD; 8 consecutive per-XCD slots share mtile
    int raw   = blockIdx.x;                 // 0..4095
    int ntile = (raw >> 3) & 7;             // 0..7
    int mtile = (raw & 7) + 8 * (raw >> 6); // 0..511
    int n0 = ntile * 128;
    long gm0 = (long)mtile * 128;           // flat row base in [B*S]
    int b = mtile >> 4;

    // ---- B staging (global_load_lds): wave w, instr j -> rows w*32+j*8+(lane>>3)
    int brow_in = lane >> 3;                       // 0..7
    int bchunk  = (lane & 7) ^ ((lane >> 3) & 7);  // source pre-swizzle
    const unsigned short* Bg =
        we_bf + (size_t)(n0 + w * 32 + brow_in) * HDIM + bchunk * 8;
    unsigned short* Bw_dst_base;  // set per STAGE

    // ---- A staging: thread -> row ra = tid>>1 (0..127), half h = tid&1 (32 cols)
    int ra = tid >> 1, h = tid & 1;
    const float* Ag = enc + (size_t)(gm0 + ra) * HDIM + h * 32;
    int aswz = ra & 7;

    f32x4 acc[4][4];
#pragma unroll
    for (int mt = 0; mt < 4; ++mt)
#pragma unroll
        for (int nt = 0; nt < 4; ++nt) acc[mt][nt] = (f32x4)0.0f;

    int arow0 = wm * 64 + i15;    // + mt*16 ; row&7 == i15&7 for all frags
    int brow0 = wn * 64 + i15;    // + nt*16

    float4 pre[8];

#define STAGE(KT, BUF) do {                                                   \
        unsigned short* bd = Bs + (BUF) * 8192 + (w * 32) * 64 + lane * 8;    \
        const unsigned short* bsrc = Bg + (size_t)(KT) * 64;                  \
        gl2lds16(bsrc,                        bd);                            \
        gl2lds16(bsrc + (size_t)8  * HDIM,    bd + 512);                      \
        gl2lds16(bsrc + (size_t)16 * HDIM,    bd + 1024);                     \
        gl2lds16(bsrc + (size_t)24 * HDIM,    bd + 1536);                     \
        const float4* ap = (const float4*)(Ag + (size_t)(KT) * 64);           \
        pre[0] = ap[0]; pre[1] = ap[1]; pre[2] = ap[2]; pre[3] = ap[3];       \
        pre[4] = ap[4]; pre[5] = ap[5]; pre[6] = ap[6]; pre[7] = ap[7];       \
    } while (0)

#define DSW(BUF) do {                                                         \
        unsigned short* ad = As + (BUF) * 8192 + ra * 64;                     \
        _Pragma("unroll")                                                     \
        for (int j = 0; j < 4; ++j) {                                         \
            float4 x = pre[2 * j], y = pre[2 * j + 1];                        \
            uint4 o;                                                          \
            o.x = pk_bf16(x.x, x.y); o.y = pk_bf16(x.z, x.w);                 \
            o.z = pk_bf16(y.x, y.y); o.w = pk_bf16(y.z, y.w);                 \
            *(uint4*)(ad + ((4 * h + j) ^ aswz) * 8) = o;                     \
        }                                                                     \
    } while (0)

    // prologue: stage K-tile 0 into buffer 0
    STAGE(0, 0);
    DSW(0);
    __syncthreads();

#pragma unroll 2
    for (int kt = 0; kt < 16; ++kt) {
        int cur = kt & 1;
        if (kt < 15) STAGE(kt + 1, cur ^ 1);   // issue loads early (T14)

        const unsigned short* Ac = As + cur * 8192;
        const unsigned short* Bc = Bs + cur * 8192;

        __builtin_amdgcn_s_setprio(1);
#pragma unroll
        for (int kk = 0; kk < 2; ++kk) {
            int xr = ((kk * 4 + q) ^ (i15 & 7)) * 8;
            short8 af[4], bf[4];
#pragma unroll
            for (int mt = 0; mt < 4; ++mt)
                af[mt] = *(const short8*)(Ac + (arow0 + mt * 16) * 64 + xr);
#pragma unroll
            for (int nt = 0; nt < 4; ++nt)
                bf[nt] = *(const short8*)(Bc + (brow0 + nt * 16) * 64 + xr);
#pragma unroll
            for (int mt = 0; mt < 4; ++mt)
#pragma unroll
                for (int nt = 0; nt < 4; ++nt)
                    acc[mt][nt] = __builtin_amdgcn_mfma_f32_16x16x32_bf16(
                        af[mt], bf[nt], acc[mt][nt], 0, 0, 0);
        }
        __builtin_amdgcn_s_setprio(0);

        if (kt < 15) {
            DSW(cur ^ 1);        // pre[] consumed after this iter's MFMA block
            __syncthreads();     // drains B gl_lds; publishes A ds_writes
        }
    }
#undef STAGE
#undef DSW

    // epilogue: C layout col=i15 (n), row=q*4+reg (m); tanh + v-dot + n-reduce
    float sc[4][4];
#pragma unroll
    for (int mt = 0; mt < 4; ++mt)
#pragma unroll
        for (int r = 0; r < 4; ++r) sc[mt][r] = 0.0f;

#pragma unroll
    for (int nt = 0; nt < 4; ++nt) {
        int n = n0 + wn * 64 + nt * 16 + i15;
        float qv = qb[(size_t)b * HDIM + n];
        float vv = v_w[n];
#pragma unroll
        for (int mt = 0; mt < 4; ++mt)
#pragma unroll
            for (int r = 0; r < 4; ++r)
                sc[mt][r] += vv * fast_tanh(acc[mt][nt][r] + qv);
    }
#pragma unroll
    for (int mt = 0; mt < 4; ++mt)
#pragma unroll
        for (int r = 0; r < 4; ++r) {
            float v = sc[mt][r];
            v += __shfl_xor(v, 1); v += __shfl_xor(v, 2);
            v += __shfl_xor(v, 4); v += __shfl_xor(v, 8);
            if (i15 == 0)
                atomicAdd(&scores[gm0 + wm * 64 + mt * 16 + q * 4 + r], v);
        }
}

// ---------------------------------------------------------------------------
// Kernel 3: softmax over S per batch; writes attn_weights, zeroes context
// slots, copies hidden.
// ---------------------------------------------------------------------------
__global__ __launch_bounds__(256) void softmax_kernel(
    const float* __restrict__ scores, const float* __restrict__ hidden,
    float* out) {
    int b = blockIdx.x, tid = threadIdx.x;
    const float* srow = scores + (size_t)b * SEQ;
    __shared__ float redm[4];
    __shared__ float reds[4];
    int lane = tid & 63, wv = tid >> 6;

    float loc[8];
    float m = -1e30f;
#pragma unroll
    for (int i = 0; i < 8; ++i) {
        loc[i] = srow[tid + i * 256];
        m = fmaxf(m, loc[i]);
    }
#pragma unroll
    for (int d = 1; d < 64; d <<= 1) m = fmaxf(m, __shfl_xor(m, d));
    if (lane == 0) redm[wv] = m;
    __syncthreads();
    m = fmaxf(fmaxf(redm[0], redm[1]), fmaxf(redm[2], redm[3]));

    float sum = 0.0f;
#pragma unroll
    for (int i = 0; i < 8; ++i) {
        float e = __expf(loc[i] - m);
        loc[i] = e;
        sum += e;
    }
#pragma unroll
    for (int d = 1; d < 64; d <<= 1) sum += __shfl_xor(sum, d);
    if (lane == 0) reds[wv] = sum;
    __syncthreads();
    sum = reds[0] + reds[1] + reds[2] + reds[3];
    float inv = 1.0f / sum;

#pragma unroll
    for (int i = 0; i < 8; ++i)
        out[BATCH * SEQ + (size_t)b * SEQ + tid + i * 256] = loc[i] * inv;

    for (int i = tid; i < HDIM; i += 256) {
        out[(size_t)b * 2048 + i] = 0.0f;
        out[(size_t)b * 2048 + 1024 + i] = hidden[(size_t)b * HDIM + i];
    }
}

// ---------------------------------------------------------------------------
// Kernel 4: context from fp32 enc. grid = 32 b x 16 s-chunks (128 rows).
// Two independent s-streams (s, s+64) for ILP; float4 per thread; atomicAdd.
// ---------------------------------------------------------------------------
__global__ __launch_bounds__(256) void context_kernel(
    const float* __restrict__ enc, const float* __restrict__ weights_src,
    float* out) {
    int id = blockIdx.x;
    int scid = id & 15, b = id >> 4;
    int tid = threadIdx.x;
    __shared__ float wl[128];
    if (tid < 128)
        wl[tid] = weights_src[BATCH * SEQ + (size_t)b * SEQ + scid * 128 + tid];
    __syncthreads();
    const float* ebase = enc + ((size_t)(b * SEQ + scid * 128)) * HDIM + tid * 4;
    float a0 = 0.f, a1 = 0.f, a2 = 0.f, a3 = 0.f;
    float b0 = 0.f, b1 = 0.f, b2 = 0.f, b3 = 0.f;
#pragma unroll 4
    for (int s = 0; s < 64; ++s) {
        float4 e0 = *(const float4*)(ebase + (size_t)s * HDIM);
        float4 e1 = *(const float4*)(ebase + (size_t)(s + 64) * HDIM);
        float w0 = wl[s], w1 = wl[s + 64];
        a0 += w0 * e0.x; a1 += w0 * e0.y; a2 += w0 * e0.z; a3 += w0 * e0.w;
        b0 += w1 * e1.x; b1 += w1 * e1.y; b2 += w1 * e1.z; b3 += w1 * e1.w;
    }
    float* o = out + (size_t)b * 2048 + tid * 4;
    atomicAdd(o + 0, a0 + b0); atomicAdd(o + 1, a1 + b1);
    atomicAdd(o + 2, a2 + b2); atomicAdd(o + 3, a3 + b3);
}

// ---------------------------------------------------------------------------
extern "C" void kernel_launch(void* const* d_in, const int* in_sizes, int n_in,
                              void* d_out, int out_size, void* d_ws, size_t ws_size,
                              hipStream_t stream) {
    const float* hidden = (const float*)d_in[0];
    const float* enc    = (const float*)d_in[1];
    const float* attn_w = (const float*)d_in[2];
    const float* attn_b = (const float*)d_in[3];
    const float* v_w    = (const float*)d_in[4];
    float* out = (float*)d_out;

    char* ws = (char*)d_ws;
    unsigned short* we_bf = (unsigned short*)ws;                     // 2 MB
    float* qb     = (float*)(ws + (size_t)2097152);                  // 128 KB
    float* scores = (float*)(ws + (size_t)2097152 + 131072);         // 256 KB

    prep_kernel<<<1024, 256, 0, stream>>>(hidden, attn_w, attn_b, we_bf, qb, scores);
    score_gemm_kernel<<<4096, 256, 0, stream>>>(enc, we_bf, qb, v_w, scores);
    softmax_kernel<<<32, 256, 0, stream>>>(scores, hidden, out);
    context_kernel<<<512, 256, 0, stream>>>(enc, out, out);
}

// Round 7
// 649.625 us; speedup vs baseline: 1.1118x; 1.1118x over previous
//
#include <hip/hip_runtime.h>
#include <stdint.h>

#define BATCH 32
#define SEQ   2048
#define HDIM  1024

typedef short short8 __attribute__((ext_vector_type(8)));
typedef float f32x4 __attribute__((ext_vector_type(4)));

__device__ __forceinline__ unsigned short f2b(float f) {
    unsigned u = __float_as_uint(f);
    u += 0x7FFFu + ((u >> 16) & 1u);   // round-to-nearest-even
    return (unsigned short)(u >> 16);
}
// pack hi16(a) | hi16(b)<<16 in one v_perm_b32 (bf16 truncation)
__device__ __forceinline__ unsigned pk_bf16(float a, float b) {
    return __builtin_amdgcn_perm(__float_as_uint(b), __float_as_uint(a), 0x07060302u);
}
__device__ __forceinline__ float fast_tanh(float x) {
    float ex = __expf(2.0f * x);
    return 1.0f - 2.0f / (ex + 1.0f);
}
__device__ __forceinline__ void gl2lds16(const unsigned short* g, unsigned short* l) {
    __builtin_amdgcn_global_load_lds(
        (const __attribute__((address_space(1))) unsigned int*)g,
        (__attribute__((address_space(3))) unsigned int*)l, 16, 0, 0);
}

// ---------------------------------------------------------------------------
// Kernel 1: per k-row (grid=1024): We row -> bf16 (RNE); qb = hidden.Wh^T + b;
// zero scores.
// ---------------------------------------------------------------------------
__global__ __launch_bounds__(256) void prep_kernel(
    const float* __restrict__ hidden, const float* __restrict__ attn_w,
    const float* __restrict__ attn_b, unsigned short* __restrict__ we_bf,
    float* __restrict__ qb, float* __restrict__ scores) {
    int k = blockIdx.x;
    int tid = threadIdx.x;

    if (tid < 64) scores[(size_t)k * 64 + tid] = 0.0f;

    {
        const float4* src = (const float4*)(attn_w + (size_t)k * 2048 + 1024);
        float4 v = src[tid];
        ushort4 o;
        o.x = f2b(v.x); o.y = f2b(v.y); o.z = f2b(v.z); o.w = f2b(v.w);
        ((ushort4*)(we_bf + (size_t)k * HDIM))[tid] = o;
    }

    float part[BATCH];
#pragma unroll
    for (int b = 0; b < BATCH; ++b) part[b] = 0.0f;
    const float* wrow = attn_w + (size_t)k * 2048;
    for (int h = tid; h < HDIM; h += 256) {
        float w = wrow[h];
#pragma unroll
        for (int b = 0; b < BATCH; ++b) part[b] += w * hidden[b * HDIM + h];
    }
    __shared__ float red[4][BATCH];
    int lane = tid & 63, wv = tid >> 6;
#pragma unroll
    for (int b = 0; b < BATCH; ++b) {
        float v = part[b];
        v += __shfl_xor(v, 1);  v += __shfl_xor(v, 2);  v += __shfl_xor(v, 4);
        v += __shfl_xor(v, 8);  v += __shfl_xor(v, 16); v += __shfl_xor(v, 32);
        if (lane == 0) red[wv][b] = v;
    }
    __syncthreads();
    if (tid < BATCH) {
        float v = red[0][tid] + red[1][tid] + red[2][tid] + red[3][tid] + attn_b[k];
        qb[(size_t)tid * HDIM + k] = v;
    }
}

// ---------------------------------------------------------------------------
// Kernel 1b: convert enc fp32 -> bf16 (truncation, same numerics as before),
// laid out as the EXACT 16KB LDS image per (mtile, kt): image[r][p][8] holds
// enc[mtile*128+r][kt*64 + (p^(r&7))*8 .. +8] -- the GEMM's XOR swizzle is
// baked into the buffer, so GEMM staging is pure linear global_load_lds.
// grid = 512 mtiles x 4 kt-groups; ~384 MB traffic, memory-bound.
// ---------------------------------------------------------------------------
__global__ __launch_bounds__(256) void convert_kernel(
    const float* __restrict__ enc, unsigned short* __restrict__ enc_bf) {
    int id = blockIdx.x;            // 0..2047
    int m = id >> 2, g = id & 3;    // mtile, kt-group
    int tid = threadIdx.x;
    int r = tid >> 1, h = tid & 1;  // row 0..127, half 0..1
    const float* src = enc + ((size_t)m * 128 + r) * HDIM;
    int r7 = r & 7;
#pragma unroll
    for (int k4 = 0; k4 < 4; ++k4) {
        int kt = g * 4 + k4;
        unsigned short* img =
            enc_bf + ((size_t)m * 16 + kt) * 8192 + r * 64 + h * 32;
#pragma unroll
        for (int p = 0; p < 4; ++p) {
            int c = (4 * h + p) ^ r7;
            const float4* s = (const float4*)(src + kt * 64 + c * 8);
            float4 x = s[0], y = s[1];
            uint4 o;
            o.x = pk_bf16(x.x, x.y); o.y = pk_bf16(x.z, x.w);
            o.z = pk_bf16(y.x, y.y); o.w = pk_bf16(y.z, y.w);
            *(uint4*)(img + p * 8) = o;
        }
    }
}

// ---------------------------------------------------------------------------
// Kernel 2: score GEMM, m97-clone structure: 128x128 tile, BK=64, 256 threads
// (4 waves 2Mx2N, wave tile 64x64 = 4x4 frags, acc 64 regs). SINGLE 32KB LDS
// buffer, 2-barrier K-loop: [compute kt] -> bar -> STAGE(kt+1) -> bar. Both
// A and B staged via global_load_lds from pre-swizzled bf16 buffers -- no
// fp32 A reads, no pack/ds_write chain in the hot loop (rounds 4/5 showed
// that chain was the stall: all pipes <20% busy). Low VGPR -> ~3 blocks/CU;
// cross-block wave overlap hides the stage drain (m114/m97: 874-912 TF on
// exactly this skeleton). Swizzle chunk^(row&7): 0 bank conflicts (verified
// rounds 4/5). XCD decode: per-XCD contiguous mtile chunks; 8 consecutive
// per-XCD slots share one mtile -> A image HBM-fetched ~once, L2-served 8x.
// ---------------------------------------------------------------------------
__global__ __launch_bounds__(256, 3) void score_gemm_kernel(
    const unsigned short* __restrict__ enc_bf,
    const unsigned short* __restrict__ we_bf,
    const float* __restrict__ qb, const float* __restrict__ v_w,
    float* __restrict__ scores) {
    __shared__ __align__(16) unsigned short As[8192];  // 128x64 bf16 = 16 KB
    __shared__ __align__(16) unsigned short Bs[8192];  // 16 KB

    int tid  = threadIdx.x;
    int lane = tid & 63, w = tid >> 6;     // 4 waves
    int wm = w & 1, wn = w >> 1;           // 2 x 2
    int i15 = lane & 15, q = lane >> 4;

    // XCD decode: xcd = raw&7; per-XCD slot i: ntile = i&7 (8 consecutive
    // slots share mtile), mtile = xcd*64 + (i>>3). Bijective over 4096.
    int raw   = blockIdx.x;
    int i     = raw >> 3;
    int ntile = i & 7;
    int mtile = (raw & 7) * 64 + (i >> 3);  // 0..511
    int n0 = ntile * 128;
    long gm0 = (long)mtile * 128;           // flat row base in [B*S]
    int b = mtile >> 4;

    // ---- B staging: wave w, instr j -> rows w*32+j*8+(lane>>3); source
    // pre-swizzled so LDS phys chunk p holds logical p^(r&7).
    int brow_in = lane >> 3;
    int bchunk  = (lane & 7) ^ ((lane >> 3) & 7);
    const unsigned short* Bg =
        we_bf + (size_t)(n0 + w * 32 + brow_in) * HDIM + bchunk * 8;
    unsigned short* Bd = Bs + (w * 32) * 64 + lane * 8;

    // ---- A staging: image is already the LDS byte pattern; pure linear copy.
    const unsigned short* Atile = enc_bf + (size_t)mtile * 16 * 8192;
    int aoff = w * 2048 + lane * 8;         // + j*512, j=0..3

    f32x4 acc[4][4];
#pragma unroll
    for (int mt = 0; mt < 4; ++mt)
#pragma unroll
        for (int nt = 0; nt < 4; ++nt) acc[mt][nt] = (f32x4)0.0f;

    int arow0 = wm * 64 + i15;    // + mt*16
    int brow0 = wn * 64 + i15;    // + nt*16

#define STAGE(KT) do {                                                        \
        const unsigned short* bsrc = Bg + (size_t)(KT) * 64;                  \
        gl2lds16(bsrc,                     Bd);                               \
        gl2lds16(bsrc + (size_t)8  * HDIM, Bd + 512);                         \
        gl2lds16(bsrc + (size_t)16 * HDIM, Bd + 1024);                        \
        gl2lds16(bsrc + (size_t)24 * HDIM, Bd + 1536);                        \
        const unsigned short* asrc = Atile + (size_t)(KT) * 8192 + aoff;      \
        unsigned short* adst = As + aoff;                                     \
        gl2lds16(asrc,        adst);                                          \
        gl2lds16(asrc + 512,  adst + 512);                                    \
        gl2lds16(asrc + 1024, adst + 1024);                                   \
        gl2lds16(asrc + 1536, adst + 1536);                                   \
    } while (0)

    // prologue
    STAGE(0);
    __syncthreads();

    for (int kt = 0; kt < 16; ++kt) {
#pragma unroll
        for (int kk = 0; kk < 2; ++kk) {
            int xr = ((kk * 4 + q) ^ (i15 & 7)) * 8;
            short8 af[4], bf[4];
#pragma unroll
            for (int mt = 0; mt < 4; ++mt)
                af[mt] = *(const short8*)(As + (arow0 + mt * 16) * 64 + xr);
#pragma unroll
            for (int nt = 0; nt < 4; ++nt)
                bf[nt] = *(const short8*)(Bs + (brow0 + nt * 16) * 64 + xr);
#pragma unroll
            for (int mt = 0; mt < 4; ++mt)
#pragma unroll
                for (int nt = 0; nt < 4; ++nt)
                    acc[mt][nt] = __builtin_amdgcn_mfma_f32_16x16x32_bf16(
                        af[mt], bf[nt], acc[mt][nt], 0, 0, 0);
        }
        if (kt < 15) {
            __syncthreads();     // all reads of the buffer done (WAR)
            STAGE(kt + 1);
            __syncthreads();     // staging visible (drains vmcnt)
        }
    }
#undef STAGE

    // epilogue: C layout col=i15 (n), row=q*4+reg (m); tanh + v-dot + n-reduce
    float sc[4][4];
#pragma unroll
    for (int mt = 0; mt < 4; ++mt)
#pragma unroll
        for (int r = 0; r < 4; ++r) sc[mt][r] = 0.0f;

#pragma unroll
    for (int nt = 0; nt < 4; ++nt) {
        int n = n0 + wn * 64 + nt * 16 + i15;
        float qv = qb[(size_t)b * HDIM + n];
        float vv = v_w[n];
#pragma unroll
        for (int mt = 0; mt < 4; ++mt)
#pragma unroll
            for (int r = 0; r < 4; ++r)
                sc[mt][r] += vv * fast_tanh(acc[mt][nt][r] + qv);
    }
#pragma unroll
    for (int mt = 0; mt < 4; ++mt)
#pragma unroll
        for (int r = 0; r < 4; ++r) {
            float v = sc[mt][r];
            v += __shfl_xor(v, 1); v += __shfl_xor(v, 2);
            v += __shfl_xor(v, 4); v += __shfl_xor(v, 8);
            if (i15 == 0)
                atomicAdd(&scores[gm0 + wm * 64 + mt * 16 + q * 4 + r], v);
        }
}

// ---------------------------------------------------------------------------
// Kernel 3: softmax over S per batch; writes attn_weights, zeroes context
// slots, copies hidden.
// ---------------------------------------------------------------------------
__global__ __launch_bounds__(256) void softmax_kernel(
    const float* __restrict__ scores, const float* __restrict__ hidden,
    float* out) {
    int b = blockIdx.x, tid = threadIdx.x;
    const float* srow = scores + (size_t)b * SEQ;
    __shared__ float redm[4];
    __shared__ float reds[4];
    int lane = tid & 63, wv = tid >> 6;

    float loc[8];
    float m = -1e30f;
#pragma unroll
    for (int i = 0; i < 8; ++i) {
        loc[i] = srow[tid + i * 256];
        m = fmaxf(m, loc[i]);
    }
#pragma unroll
    for (int d = 1; d < 64; d <<= 1) m = fmaxf(m, __shfl_xor(m, d));
    if (lane == 0) redm[wv] = m;
    __syncthreads();
    m = fmaxf(fmaxf(redm[0], redm[1]), fmaxf(redm[2], redm[3]));

    float sum = 0.0f;
#pragma unroll
    for (int i = 0; i < 8; ++i) {
        float e = __expf(loc[i] - m);
        loc[i] = e;
        sum += e;
    }
#pragma unroll
    for (int d = 1; d < 64; d <<= 1) sum += __shfl_xor(sum, d);
    if (lane == 0) reds[wv] = sum;
    __syncthreads();
    sum = reds[0] + reds[1] + reds[2] + reds[3];
    float inv = 1.0f / sum;

#pragma unroll
    for (int i = 0; i < 8; ++i)
        out[BATCH * SEQ + (size_t)b * SEQ + tid + i * 256] = loc[i] * inv;

    for (int i = tid; i < HDIM; i += 256) {
        out[(size_t)b * 2048 + i] = 0.0f;
        out[(size_t)b * 2048 + 1024 + i] = hidden[(size_t)b * HDIM + i];
    }
}

// ---------------------------------------------------------------------------
// Kernel 4: context from fp32 enc. grid = 32 b x 16 s-chunks (128 rows).
// Two independent s-streams (s, s+64) for ILP; float4 per thread; atomicAdd.
// ---------------------------------------------------------------------------
__global__ __launch_bounds__(256) void context_kernel(
    const float* __restrict__ enc, const float* __restrict__ weights_src,
    float* out) {
    int id = blockIdx.x;
    int scid = id & 15, b = id >> 4;
    int tid = threadIdx.x;
    __shared__ float wl[128];
    if (tid < 128)
        wl[tid] = weights_src[BATCH * SEQ + (size_t)b * SEQ + scid * 128 + tid];
    __syncthreads();
    const float* ebase = enc + ((size_t)(b * SEQ + scid * 128)) * HDIM + tid * 4;
    float a0 = 0.f, a1 = 0.f, a2 = 0.f, a3 = 0.f;
    float b0 = 0.f, b1 = 0.f, b2 = 0.f, b3 = 0.f;
#pragma unroll 4
    for (int s = 0; s < 64; ++s) {
        float4 e0 = *(const float4*)(ebase + (size_t)s * HDIM);
        float4 e1 = *(const float4*)(ebase + (size_t)(s + 64) * HDIM);
        float w0 = wl[s], w1 = wl[s + 64];
        a0 += w0 * e0.x; a1 += w0 * e0.y; a2 += w0 * e0.z; a3 += w0 * e0.w;
        b0 += w1 * e1.x; b1 += w1 * e1.y; b2 += w1 * e1.z; b3 += w1 * e1.w;
    }
    float* o = out + (size_t)b * 2048 + tid * 4;
    atomicAdd(o + 0, a0 + b0); atomicAdd(o + 1, a1 + b1);
    atomicAdd(o + 2, a2 + b2); atomicAdd(o + 3, a3 + b3);
}

// ---------------------------------------------------------------------------
extern "C" void kernel_launch(void* const* d_in, const int* in_sizes, int n_in,
                              void* d_out, int out_size, void* d_ws, size_t ws_size,
                              hipStream_t stream) {
    const float* hidden = (const float*)d_in[0];
    const float* enc    = (const float*)d_in[1];
    const float* attn_w = (const float*)d_in[2];
    const float* attn_b = (const float*)d_in[3];
    const float* v_w    = (const float*)d_in[4];
    float* out = (float*)d_out;

    char* ws = (char*)d_ws;
    unsigned short* enc_bf = (unsigned short*)ws;                        // 128 MB
    unsigned short* we_bf  = (unsigned short*)(ws + (size_t)134217728);  // 2 MB
    float* qb     = (float*)(ws + (size_t)134217728 + 2097152);          // 128 KB
    float* scores = (float*)(ws + (size_t)134217728 + 2097152 + 131072); // 256 KB

    prep_kernel<<<1024, 256, 0, stream>>>(hidden, attn_w, attn_b, we_bf, qb, scores);
    convert_kernel<<<2048, 256, 0, stream>>>(enc, enc_bf);
    score_gemm_kernel<<<4096, 256, 0, stream>>>(enc_bf, we_bf, qb, v_w, scores);
    softmax_kernel<<<32, 256, 0, stream>>>(scores, hidden, out);
    context_kernel<<<512, 256, 0, stream>>>(enc, out, out);
}

// Round 8
// 630.558 us; speedup vs baseline: 1.1454x; 1.0302x over previous
//
#include <hip/hip_runtime.h>
#include <stdint.h>

#define BATCH 32
#define SEQ   2048
#define HDIM  1024

typedef short short8 __attribute__((ext_vector_type(8)));
typedef float f32x4 __attribute__((ext_vector_type(4)));

__device__ __forceinline__ unsigned short f2b(float f) {
    unsigned u = __float_as_uint(f);
    u += 0x7FFFu + ((u >> 16) & 1u);   // round-to-nearest-even
    return (unsigned short)(u >> 16);
}
// pack hi16(a) | hi16(b)<<16 in one v_perm_b32 (bf16 truncation)
__device__ __forceinline__ unsigned pk_bf16(float a, float b) {
    return __builtin_amdgcn_perm(__float_as_uint(b), __float_as_uint(a), 0x07060302u);
}
__device__ __forceinline__ float fast_tanh(float x) {
    float ex = __expf(2.0f * x);
    return 1.0f - 2.0f / (ex + 1.0f);
}
__device__ __forceinline__ void gl2lds16(const unsigned short* g, unsigned short* l) {
    __builtin_amdgcn_global_load_lds(
        (const __attribute__((address_space(1))) unsigned int*)g,
        (__attribute__((address_space(3))) unsigned int*)l, 16, 0, 0);
}

// ---------------------------------------------------------------------------
// Kernel 1 (fused prep + convert): block-role split so the BW-bound enc
// conversion overlaps the VALU-ish prep instead of serializing.
//   blocks 0..2047   : convert role -- enc fp32 -> bf16 (truncation), laid
//     out as the EXACT 16KB LDS image per (mtile, kt): image[r][p][8] holds
//     enc[m*128+r][kt*64 + (p^(r&7))*8 .. +8] (GEMM swizzle baked in).
//   blocks 2048..3071: prep role (k = bid-2048) -- We row k -> bf16 (RNE);
//     qb = hidden.Wh^T + b; zero scores row.
// ---------------------------------------------------------------------------
__global__ __launch_bounds__(256) void prep_convert_kernel(
    const float* __restrict__ hidden, const float* __restrict__ attn_w,
    const float* __restrict__ attn_b, const float* __restrict__ enc,
    unsigned short* __restrict__ we_bf, unsigned short* __restrict__ enc_bf,
    float* __restrict__ qb, float* __restrict__ scores) {
    int bid = blockIdx.x;
    int tid = threadIdx.x;
    __shared__ float red[4][BATCH];

    if (bid < 2048) {
        // ---- convert role ----
        int m = bid >> 2, g = bid & 3;    // mtile, kt-group
        int r = tid >> 1, h = tid & 1;    // row 0..127, half 0..1
        const float* src = enc + ((size_t)m * 128 + r) * HDIM;
        int r7 = r & 7;
#pragma unroll
        for (int k4 = 0; k4 < 4; ++k4) {
            int kt = g * 4 + k4;
            unsigned short* img =
                enc_bf + ((size_t)m * 16 + kt) * 8192 + r * 64 + h * 32;
#pragma unroll
            for (int p = 0; p < 4; ++p) {
                int c = (4 * h + p) ^ r7;
                const float4* s = (const float4*)(src + kt * 64 + c * 8);
                float4 x = s[0], y = s[1];
                uint4 o;
                o.x = pk_bf16(x.x, x.y); o.y = pk_bf16(x.z, x.w);
                o.z = pk_bf16(y.x, y.y); o.w = pk_bf16(y.z, y.w);
                *(uint4*)(img + p * 8) = o;
            }
        }
        return;
    }

    // ---- prep role ----
    int k = bid - 2048;
    if (tid < 64) scores[(size_t)k * 64 + tid] = 0.0f;

    {
        const float4* src = (const float4*)(attn_w + (size_t)k * 2048 + 1024);
        float4 v = src[tid];
        ushort4 o;
        o.x = f2b(v.x); o.y = f2b(v.y); o.z = f2b(v.z); o.w = f2b(v.w);
        ((ushort4*)(we_bf + (size_t)k * HDIM))[tid] = o;
    }

    float part[BATCH];
#pragma unroll
    for (int b = 0; b < BATCH; ++b) part[b] = 0.0f;
    const float* wrow = attn_w + (size_t)k * 2048;
    for (int h = tid; h < HDIM; h += 256) {
        float w = wrow[h];
#pragma unroll
        for (int b = 0; b < BATCH; ++b) part[b] += w * hidden[b * HDIM + h];
    }
    int lane = tid & 63, wv = tid >> 6;
#pragma unroll
    for (int b = 0; b < BATCH; ++b) {
        float v = part[b];
        v += __shfl_xor(v, 1);  v += __shfl_xor(v, 2);  v += __shfl_xor(v, 4);
        v += __shfl_xor(v, 8);  v += __shfl_xor(v, 16); v += __shfl_xor(v, 32);
        if (lane == 0) red[wv][b] = v;
    }
    __syncthreads();
    if (tid < BATCH) {
        float v = red[0][tid] + red[1][tid] + red[2][tid] + red[3][tid] + attn_b[k];
        qb[(size_t)tid * HDIM + k] = v;
    }
}

// ---------------------------------------------------------------------------
// Kernel 2: score GEMM, m97-clone structure: 128x128 tile, BK=64, 256 threads
// (4 waves 2Mx2N, wave tile 64x64 = 4x4 frags, acc 64 regs). SINGLE 32KB LDS
// buffer, 2-barrier K-loop. Both A and B staged via global_load_lds from
// pre-swizzled bf16 buffers. Round-7 profile: 180us, MfmaUtil 35%, occ 37%
// (= the 3 blocks/CU my own launch_bounds requested), 0 bank conflicts,
// FETCH 79MB (XCD A-sharing works). VGPR=60 and LDS 32KB permit 5 blocks/CU
// (160KB exactly) -> bump min-blocks to 5 for more cross-block MFMA overlap
// to absorb each block's stage drain (m114 mechanism).
// ---------------------------------------------------------------------------
__global__ __launch_bounds__(256, 5) void score_gemm_kernel(
    const unsigned short* __restrict__ enc_bf,
    const unsigned short* __restrict__ we_bf,
    const float* __restrict__ qb, const float* __restrict__ v_w,
    float* __restrict__ scores) {
    __shared__ __align__(16) unsigned short As[8192];  // 128x64 bf16 = 16 KB
    __shared__ __align__(16) unsigned short Bs[8192];  // 16 KB

    int tid  = threadIdx.x;
    int lane = tid & 63, w = tid >> 6;     // 4 waves
    int wm = w & 1, wn = w >> 1;           // 2 x 2
    int i15 = lane & 15, q = lane >> 4;

    // XCD decode: xcd = raw&7; per-XCD slot i: ntile = i&7 (8 consecutive
    // slots share mtile), mtile = xcd*64 + (i>>3). Bijective over 4096.
    int raw   = blockIdx.x;
    int i     = raw >> 3;
    int ntile = i & 7;
    int mtile = (raw & 7) * 64 + (i >> 3);  // 0..511
    int n0 = ntile * 128;
    long gm0 = (long)mtile * 128;           // flat row base in [B*S]
    int b = mtile >> 4;

    // ---- B staging: wave w, instr j -> rows w*32+j*8+(lane>>3); source
    // pre-swizzled so LDS phys chunk p holds logical p^(r&7).
    int brow_in = lane >> 3;
    int bchunk  = (lane & 7) ^ ((lane >> 3) & 7);
    const unsigned short* Bg =
        we_bf + (size_t)(n0 + w * 32 + brow_in) * HDIM + bchunk * 8;
    unsigned short* Bd = Bs + (w * 32) * 64 + lane * 8;

    // ---- A staging: image is already the LDS byte pattern; pure linear copy.
    const unsigned short* Atile = enc_bf + (size_t)mtile * 16 * 8192;
    int aoff = w * 2048 + lane * 8;         // + j*512, j=0..3

    f32x4 acc[4][4];
#pragma unroll
    for (int mt = 0; mt < 4; ++mt)
#pragma unroll
        for (int nt = 0; nt < 4; ++nt) acc[mt][nt] = (f32x4)0.0f;

    int arow0 = wm * 64 + i15;    // + mt*16
    int brow0 = wn * 64 + i15;    // + nt*16

#define STAGE(KT) do {                                                        \
        const unsigned short* bsrc = Bg + (size_t)(KT) * 64;                  \
        gl2lds16(bsrc,                     Bd);                               \
        gl2lds16(bsrc + (size_t)8  * HDIM, Bd + 512);                         \
        gl2lds16(bsrc + (size_t)16 * HDIM, Bd + 1024);                        \
        gl2lds16(bsrc + (size_t)24 * HDIM, Bd + 1536);                        \
        const unsigned short* asrc = Atile + (size_t)(KT) * 8192 + aoff;      \
        unsigned short* adst = As + aoff;                                     \
        gl2lds16(asrc,        adst);                                          \
        gl2lds16(asrc + 512,  adst + 512);                                    \
        gl2lds16(asrc + 1024, adst + 1024);                                   \
        gl2lds16(asrc + 1536, adst + 1536);                                   \
    } while (0)

    // prologue
    STAGE(0);
    __syncthreads();

    for (int kt = 0; kt < 16; ++kt) {
#pragma unroll
        for (int kk = 0; kk < 2; ++kk) {
            int xr = ((kk * 4 + q) ^ (i15 & 7)) * 8;
            short8 af[4], bf[4];
#pragma unroll
            for (int mt = 0; mt < 4; ++mt)
                af[mt] = *(const short8*)(As + (arow0 + mt * 16) * 64 + xr);
#pragma unroll
            for (int nt = 0; nt < 4; ++nt)
                bf[nt] = *(const short8*)(Bs + (brow0 + nt * 16) * 64 + xr);
#pragma unroll
            for (int mt = 0; mt < 4; ++mt)
#pragma unroll
                for (int nt = 0; nt < 4; ++nt)
                    acc[mt][nt] = __builtin_amdgcn_mfma_f32_16x16x32_bf16(
                        af[mt], bf[nt], acc[mt][nt], 0, 0, 0);
        }
        if (kt < 15) {
            __syncthreads();     // all reads of the buffer done (WAR)
            STAGE(kt + 1);
            __syncthreads();     // staging visible (drains vmcnt)
        }
    }
#undef STAGE

    // epilogue: C layout col=i15 (n), row=q*4+reg (m); tanh + v-dot + n-reduce
    float sc[4][4];
#pragma unroll
    for (int mt = 0; mt < 4; ++mt)
#pragma unroll
        for (int r = 0; r < 4; ++r) sc[mt][r] = 0.0f;

#pragma unroll
    for (int nt = 0; nt < 4; ++nt) {
        int n = n0 + wn * 64 + nt * 16 + i15;
        float qv = qb[(size_t)b * HDIM + n];
        float vv = v_w[n];
#pragma unroll
        for (int mt = 0; mt < 4; ++mt)
#pragma unroll
            for (int r = 0; r < 4; ++r)
                sc[mt][r] += vv * fast_tanh(acc[mt][nt][r] + qv);
    }
#pragma unroll
    for (int mt = 0; mt < 4; ++mt)
#pragma unroll
        for (int r = 0; r < 4; ++r) {
            float v = sc[mt][r];
            v += __shfl_xor(v, 1); v += __shfl_xor(v, 2);
            v += __shfl_xor(v, 4); v += __shfl_xor(v, 8);
            if (i15 == 0)
                atomicAdd(&scores[gm0 + wm * 64 + mt * 16 + q * 4 + r], v);
        }
}

// ---------------------------------------------------------------------------
// Kernel 3: per-batch softmax STATS only (m, 1/sum) -- identical reduction
// order to the old softmax kernel (same bits). Also zeroes the context slots
// and copies hidden (runs before context in stream order).
// ---------------------------------------------------------------------------
__global__ __launch_bounds__(256) void softmax_stats_kernel(
    const float* __restrict__ scores, const float* __restrict__ hidden,
    float* __restrict__ stats, float* out) {
    int b = blockIdx.x, tid = threadIdx.x;
    const float* srow = scores + (size_t)b * SEQ;
    __shared__ float redm[4];
    __shared__ float reds[4];
    int lane = tid & 63, wv = tid >> 6;

    float loc[8];
    float m = -1e30f;
#pragma unroll
    for (int i = 0; i < 8; ++i) {
        loc[i] = srow[tid + i * 256];
        m = fmaxf(m, loc[i]);
    }
#pragma unroll
    for (int d = 1; d < 64; d <<= 1) m = fmaxf(m, __shfl_xor(m, d));
    if (lane == 0) redm[wv] = m;
    __syncthreads();
    m = fmaxf(fmaxf(redm[0], redm[1]), fmaxf(redm[2], redm[3]));

    float sum = 0.0f;
#pragma unroll
    for (int i = 0; i < 8; ++i) sum += __expf(loc[i] - m);
#pragma unroll
    for (int d = 1; d < 64; d <<= 1) sum += __shfl_xor(sum, d);
    if (lane == 0) reds[wv] = sum;
    __syncthreads();
    if (tid == 0) {
        float s = reds[0] + reds[1] + reds[2] + reds[3];
        stats[2 * b]     = m;
        stats[2 * b + 1] = 1.0f / s;
    }

    for (int i = tid; i < HDIM; i += 256) {
        out[(size_t)b * 2048 + i] = 0.0f;
        out[(size_t)b * 2048 + 1024 + i] = hidden[(size_t)b * HDIM + i];
    }
}

// ---------------------------------------------------------------------------
// Kernel 4: context + inline softmax finish. grid = 32 b x 16 s-chunks (128
// rows). Computes w = expf(s-m)*inv (identical bits to the old two-pass
// path), writes the attn_weights output, stages w in LDS, then streams enc
// with two independent s-streams; atomicAdd partials into the zeroed slots.
// ---------------------------------------------------------------------------
__global__ __launch_bounds__(256) void context_kernel(
    const float* __restrict__ enc, const float* __restrict__ scores,
    const float* __restrict__ stats, float* out) {
    int id = blockIdx.x;
    int scid = id & 15, b = id >> 4;
    int tid = threadIdx.x;
    __shared__ float wl[128];
    float m = stats[2 * b], inv = stats[2 * b + 1];
    if (tid < 128) {
        float s = scores[(size_t)b * SEQ + scid * 128 + tid];
        float wgt = __expf(s - m) * inv;
        wl[tid] = wgt;
        out[BATCH * SEQ + (size_t)b * SEQ + scid * 128 + tid] = wgt;
    }
    __syncthreads();
    const float* ebase = enc + ((size_t)(b * SEQ + scid * 128)) * HDIM + tid * 4;
    float a0 = 0.f, a1 = 0.f, a2 = 0.f, a3 = 0.f;
    float b0 = 0.f, b1 = 0.f, b2 = 0.f, b3 = 0.f;
#pragma unroll 4
    for (int s = 0; s < 64; ++s) {
        float4 e0 = *(const float4*)(ebase + (size_t)s * HDIM);
        float4 e1 = *(const float4*)(ebase + (size_t)(s + 64) * HDIM);
        float w0 = wl[s], w1 = wl[s + 64];
        a0 += w0 * e0.x; a1 += w0 * e0.y; a2 += w0 * e0.z; a3 += w0 * e0.w;
        b0 += w1 * e1.x; b1 += w1 * e1.y; b2 += w1 * e1.z; b3 += w1 * e1.w;
    }
    float* o = out + (size_t)b * 2048 + tid * 4;
    atomicAdd(o + 0, a0 + b0); atomicAdd(o + 1, a1 + b1);
    atomicAdd(o + 2, a2 + b2); atomicAdd(o + 3, a3 + b3);
}

// ---------------------------------------------------------------------------
extern "C" void kernel_launch(void* const* d_in, const int* in_sizes, int n_in,
                              void* d_out, int out_size, void* d_ws, size_t ws_size,
                              hipStream_t stream) {
    const float* hidden = (const float*)d_in[0];
    const float* enc    = (const float*)d_in[1];
    const float* attn_w = (const float*)d_in[2];
    const float* attn_b = (const float*)d_in[3];
    const float* v_w    = (const float*)d_in[4];
    float* out = (float*)d_out;

    char* ws = (char*)d_ws;
    unsigned short* enc_bf = (unsigned short*)ws;                        // 128 MB
    unsigned short* we_bf  = (unsigned short*)(ws + (size_t)134217728);  // 2 MB
    float* qb     = (float*)(ws + (size_t)134217728 + 2097152);          // 128 KB
    float* scores = (float*)(ws + (size_t)134217728 + 2097152 + 131072); // 256 KB
    float* stats  = (float*)(ws + (size_t)134217728 + 2097152 + 131072 + 262144); // 256 B

    prep_convert_kernel<<<3072, 256, 0, stream>>>(hidden, attn_w, attn_b, enc,
                                                  we_bf, enc_bf, qb, scores);
    score_gemm_kernel<<<4096, 256, 0, stream>>>(enc_bf, we_bf, qb, v_w, scores);
    softmax_stats_kernel<<<32, 256, 0, stream>>>(scores, hidden, stats, out);
    context_kernel<<<512, 256, 0, stream>>>(enc, scores, stats, out);
}